// Round 1
// baseline (606.937 us; speedup 1.0000x reference)
//
#include <hip/hip_runtime.h>
#include <math.h>

#define H 256
#define W 256
#define NB 8
#define CIN 64
#define COUT 128

// ---------------------------------------------------------------------------
// Kernel A: offset conv (only first 3 output channels needed) + tanh + cumsum
// combos -> y_new[n][k][i][j], k in 0..2:
//   y_new[0]=t0+t1, y_new[1]=t1, y_new[2]=t1+t2   (t_k = tanh(conv_k))
// grid: (jt=8, it=8, n=8), block 256. Each thread: 1 row x 4 cols of a 32x32
// output tile. x tile (34x34, stride 35 to de-pattern banks) staged in LDS
// per input channel.
// ---------------------------------------------------------------------------
__global__ __launch_bounds__(256) void koffset(const float* __restrict__ x,
                                               const float* __restrict__ offw,
                                               float* __restrict__ ynew) {
    __shared__ float tile[34 * 35];
    const int n = blockIdx.z;
    const int i0 = blockIdx.y * 32;
    const int j0 = blockIdx.x * 32;
    const int tid = threadIdx.x;
    const int li = tid >> 3;         // 0..31 (tile row)
    const int lj4 = (tid & 7) * 4;   // 0,4,...,28 (tile col base)

    float acc[3][4];
#pragma unroll
    for (int k = 0; k < 3; ++k)
#pragma unroll
        for (int d = 0; d < 4; ++d) acc[k][d] = 0.f;

    for (int ci = 0; ci < CIN; ++ci) {
        __syncthreads();
        const float* xp = x + ((size_t)(n * CIN + ci)) * (H * W);
        for (int p = tid; p < 34 * 34; p += 256) {
            int a = p / 34, b = p - a * 34;
            int gi = i0 - 1 + a, gj = j0 - 1 + b;
            float v = 0.f;
            if ((unsigned)gi < (unsigned)H && (unsigned)gj < (unsigned)W)
                v = xp[gi * W + gj];
            tile[a * 35 + b] = v;
        }
        __syncthreads();
        const float* wp = offw + ci * 9;  // offw[k][ci][u][v]: k*576 + ci*9 + u*3 + v
#pragma unroll
        for (int u = 0; u < 3; ++u) {
            float row[6];
#pragma unroll
            for (int m = 0; m < 6; ++m) row[m] = tile[(li + u) * 35 + lj4 + m];
#pragma unroll
            for (int k = 0; k < 3; ++k) {
                float w0 = wp[k * 576 + u * 3 + 0];
                float w1 = wp[k * 576 + u * 3 + 1];
                float w2 = wp[k * 576 + u * 3 + 2];
#pragma unroll
                for (int d = 0; d < 4; ++d)
                    acc[k][d] += row[d] * w0 + row[d + 1] * w1 + row[d + 2] * w2;
            }
        }
    }

    // epilogue: tanh + cumsum combos, vectorized stores
    const int gi = i0 + li;
    const int gj = j0 + lj4;
    float4 o0, o1, o2;
    float t0[4], t1[4], t2[4];
#pragma unroll
    for (int d = 0; d < 4; ++d) {
        t0[d] = tanhf(acc[0][d]);
        t1[d] = tanhf(acc[1][d]);
        t2[d] = tanhf(acc[2][d]);
    }
    o0 = make_float4(t0[0] + t1[0], t0[1] + t1[1], t0[2] + t1[2], t0[3] + t1[3]);
    o1 = make_float4(t1[0], t1[1], t1[2], t1[3]);
    o2 = make_float4(t1[0] + t2[0], t1[1] + t2[1], t1[2] + t2[2], t1[3] + t2[3]);
    size_t base = ((size_t)n * 3) * (H * W) + (size_t)gi * W + gj;
    *(float4*)(ynew + base) = o0;
    *(float4*)(ynew + base + (size_t)H * W) = o1;
    *(float4*)(ynew + base + (size_t)2 * H * W) = o2;
}

// ---------------------------------------------------------------------------
// Kernel B: P[n][co][t] = sum_ci conv_w[co][ci][r] * x[n][ci][y][0],
// t = r*4+y, r in 0..2, y in 0..3. Only rows 0..3 of column 0 of x matter.
// grid: 8 blocks (n), 256 threads.
// ---------------------------------------------------------------------------
__global__ __launch_bounds__(256) void kpmat(const float* __restrict__ x,
                                             const float* __restrict__ convw,
                                             float* __restrict__ P) {
    __shared__ float xl[CIN * 4];
    const int n = blockIdx.x;
    const int tid = threadIdx.x;
    {
        int ci = tid >> 2, y = tid & 3;
        xl[tid] = x[(((size_t)n * CIN + ci) * H + y) * W + 0];
    }
    __syncthreads();
    const int co = tid & 127;
    const int half = tid >> 7;  // 0..1
#pragma unroll
    for (int e = 0; e < 6; ++e) {
        int t = half * 6 + e;
        int r = t >> 2;
        int y = t & 3;
        float s = 0.f;
        for (int ci = 0; ci < CIN; ++ci)
            s += convw[(co * CIN + ci) * 3 + r] * xl[ci * 4 + y];
        P[((size_t)n * COUT + co) * 12 + t] = s;
    }
}

// ---------------------------------------------------------------------------
// Kernel C: out[n,co,i,j] = sum_t C[t](n,i,j) * P[n,t,co]  (rank-12)
// grid: (i=256, n=8), block 256. Phase 1: thread j computes its 12 coeffs.
// Phase 2: 4 waves x 32 co each; per co: broadcast P (12 floats) + 48 FMA;
// float4 coalesced stores.
// ---------------------------------------------------------------------------
__global__ __launch_bounds__(256) void kout(const float* __restrict__ ynew,
                                            const float* __restrict__ P,
                                            float* __restrict__ out) {
    __shared__ float Cs[12 * 256];
    __shared__ float Pl[128 * 16];
    const int n = blockIdx.y;
    const int i = blockIdx.x;
    const int tid = threadIdx.x;

    // load P slice for this n: 128x12 -> [co][16] padded
    for (int p = tid; p < 128 * 12; p += 256) {
        int co = p / 12, t = p - co * 12;
        Pl[co * 16 + t] = P[(size_t)n * COUT * 12 + p];
    }

    // coefficients for j = tid
    {
        const int j = tid;
        float c[12];
#pragma unroll
        for (int t = 0; t < 12; ++t) c[t] = 0.f;
#pragma unroll
        for (int r = 0; r < 3; ++r) {
            int rowi = 3 * i + r;
            int k = rowi >> 8;
            int i2 = rowi & 255;
            float g = (float)(((k + i2 + j) % 3) - 1) +
                      ynew[((size_t)n * 3 + k) * (H * W) + i2 * W + j];
            // match reference arithmetic exactly:
            float gy = g / 127.5f - 1.0f;
            float iy = ((gy + 1.0f) * 256.0f - 1.0f) * 0.5f;
            float fy = floorf(iy);
            int y0 = (int)fy;
            float w1 = iy - fy;
            if ((unsigned)y0 < 4u) c[r * 4 + y0] += 0.5f * (1.0f - w1);
            int y1 = y0 + 1;
            if ((unsigned)y1 < 4u) c[r * 4 + y1] += 0.5f * w1;
        }
#pragma unroll
        for (int t = 0; t < 12; ++t) Cs[t * 256 + j] = c[t];
    }
    __syncthreads();

    const int jq = (tid & 63) * 4;  // j base, lanes cover 0..252
    const int cg = tid >> 6;        // wave id -> co group
    float4 cc[12];
#pragma unroll
    for (int t = 0; t < 12; ++t) cc[t] = *(const float4*)&Cs[t * 256 + jq];

    float* op = out + (((size_t)n * COUT) * H + i) * W;
    for (int co = cg * 32; co < cg * 32 + 32; ++co) {
        const float4* pp = (const float4*)&Pl[co * 16];
        float4 P0 = pp[0], P1 = pp[1], P2 = pp[2];
        float pv[12] = {P0.x, P0.y, P0.z, P0.w, P1.x, P1.y, P1.z, P1.w,
                        P2.x, P2.y, P2.z, P2.w};
        float4 a = make_float4(0.f, 0.f, 0.f, 0.f);
#pragma unroll
        for (int t = 0; t < 12; ++t) {
            a.x += pv[t] * cc[t].x;
            a.y += pv[t] * cc[t].y;
            a.z += pv[t] * cc[t].z;
            a.w += pv[t] * cc[t].w;
        }
        *(float4*)(op + (size_t)co * (H * W) + jq) = a;
    }
}

// ---------------------------------------------------------------------------
extern "C" void kernel_launch(void* const* d_in, const int* in_sizes, int n_in,
                              void* d_out, int out_size, void* d_ws, size_t ws_size,
                              hipStream_t stream) {
    const float* x = (const float*)d_in[0];      // [8,64,256,256]
    const float* offw = (const float*)d_in[1];   // [6,64,3,3]
    const float* convw = (const float*)d_in[2];  // [128,64,3,1]
    float* out = (float*)d_out;                  // [8,128,256,256]

    float* ynew = (float*)d_ws;                                    // 8*3*256*256 floats
    float* P = (float*)((char*)d_ws + (size_t)NB * 3 * H * W * 4); // 8*128*12 floats

    koffset<<<dim3(8, 8, 8), 256, 0, stream>>>(x, offw, ynew);
    kpmat<<<dim3(8), 256, 0, stream>>>(x, convw, P);
    kout<<<dim3(256, 8), 256, 0, stream>>>(ynew, P, out);
}

// Round 2
// 392.725 us; speedup vs baseline: 1.5454x; 1.5454x over previous
//
#include <hip/hip_runtime.h>
#include <math.h>

#define H 256
#define W 256
#define NB 8
#define CIN 64
#define COUT 128
#define G 2          // channel groups for koffset
#define CPG 32       // channels per group

typedef float f4v __attribute__((ext_vector_type(4)));

// ---------------------------------------------------------------------------
// Kernel A: offset conv (channels 0..2 only), channel-split into G=2 groups.
// Writes PRE-TANH partial sums part[g][n][k][i][j]. Double-buffered LDS tile,
// float4 global loads, one barrier per channel.
// Tile: rows i0-1..i0+32 (34), cols j0-4..j0+35 (40 floats = 10 float4/row).
// LDS layout is fully contiguous (stride 40 floats = 10 vec4), so the vec4
// index p maps to LDS offset p*16 directly.
// ---------------------------------------------------------------------------
__global__ __launch_bounds__(256) void koffset(const float* __restrict__ x,
                                               const float* __restrict__ offw,
                                               float* __restrict__ part) {
    __shared__ float tile[2][34 * 40];
    const int g = blockIdx.z & (G - 1);
    const int n = blockIdx.z / G;
    const int i0 = blockIdx.y * 32;
    const int j0 = blockIdx.x * 32;
    const int tid = threadIdx.x;
    const int li = tid >> 3;        // 0..31 output row in tile
    const int lj4 = (tid & 7) * 4;  // output col quad base

    // vec4 load assignments: p = tid and p+256 (if < 340)
    const int a1 = tid / 10, cv1 = tid - a1 * 10;
    const int p2 = tid + 256;
    const int a2 = p2 / 10, cv2 = p2 - a2 * 10;
    const bool have2 = (p2 < 340);

    const float* xbase = x + ((size_t)(n * CIN + g * CPG)) * (H * W);

    auto ld = [&](int a, int cv, const float* xp) -> float4 {
        int gi = i0 - 1 + a;
        int gj = j0 - 4 + cv * 4;
        if ((unsigned)gi < (unsigned)H && (unsigned)gj < (unsigned)W)
            return *(const float4*)(xp + gi * W + gj);
        return make_float4(0.f, 0.f, 0.f, 0.f);
    };

    float acc[3][4];
#pragma unroll
    for (int k = 0; k < 3; ++k)
#pragma unroll
        for (int d = 0; d < 4; ++d) acc[k][d] = 0.f;

    float4 r1 = ld(a1, cv1, xbase);
    float4 r2 = have2 ? ld(a2, cv2, xbase) : make_float4(0, 0, 0, 0);

    for (int c = 0; c < CPG; ++c) {
        float* buf = tile[c & 1];
        *(float4*)(buf + tid * 4) = r1;
        if (have2) *(float4*)(buf + p2 * 4) = r2;
        float4 r1n, r2n;
        if (c < CPG - 1) {
            const float* xpn = xbase + (size_t)(c + 1) * (H * W);
            r1n = ld(a1, cv1, xpn);
            r2n = have2 ? ld(a2, cv2, xpn) : make_float4(0, 0, 0, 0);
        }
        __syncthreads();  // buf visible; also guards buffer reuse (2-deep)
        const float* wp = offw + (g * CPG + c) * 9;  // offw[k][ci][u][v]
#pragma unroll
        for (int u = 0; u < 3; ++u) {
            float row[6];
#pragma unroll
            for (int m = 0; m < 6; ++m) row[m] = buf[(li + u) * 40 + 3 + lj4 + m];
#pragma unroll
            for (int k = 0; k < 3; ++k) {
                float w0 = wp[k * 576 + u * 3 + 0];
                float w1 = wp[k * 576 + u * 3 + 1];
                float w2 = wp[k * 576 + u * 3 + 2];
#pragma unroll
                for (int d = 0; d < 4; ++d)
                    acc[k][d] += row[d] * w0 + row[d + 1] * w1 + row[d + 2] * w2;
            }
        }
        r1 = r1n;
        r2 = r2n;
    }

    size_t base = (((size_t)g * NB + n) * 3) * (H * W) + (size_t)(i0 + li) * W + (j0 + lj4);
#pragma unroll
    for (int k = 0; k < 3; ++k) {
        float4 o = make_float4(acc[k][0], acc[k][1], acc[k][2], acc[k][3]);
        *(float4*)(part + base + (size_t)k * (H * W)) = o;
    }
}

// ---------------------------------------------------------------------------
// Kernel A2: reduce partials across groups, tanh, cumsum combos -> ynew.
//   t_k = tanh(sum_g part[g][k]);  y0 = t0+t1, y1 = t1, y2 = t1+t2
// grid: 512 blocks x 256 threads, float4 per thread.
// ---------------------------------------------------------------------------
__global__ __launch_bounds__(256) void kreduce(const float* __restrict__ part,
                                               float* __restrict__ ynew) {
    int idx = blockIdx.x * 256 + threadIdx.x;  // 0 .. 8*16384-1
    int n = idx >> 14;
    int hw4 = idx & 16383;
    size_t off = (size_t)hw4 * 4;
    float t[3][4];
#pragma unroll
    for (int k = 0; k < 3; ++k) {
        float4 s0 = *(const float4*)(part + (((size_t)0 * NB + n) * 3 + k) * (H * W) + off);
        float4 s1 = *(const float4*)(part + (((size_t)1 * NB + n) * 3 + k) * (H * W) + off);
        t[k][0] = tanhf(s0.x + s1.x);
        t[k][1] = tanhf(s0.y + s1.y);
        t[k][2] = tanhf(s0.z + s1.z);
        t[k][3] = tanhf(s0.w + s1.w);
    }
    size_t base = ((size_t)n * 3) * (H * W) + off;
    *(float4*)(ynew + base) =
        make_float4(t[0][0] + t[1][0], t[0][1] + t[1][1], t[0][2] + t[1][2], t[0][3] + t[1][3]);
    *(float4*)(ynew + base + (size_t)(H * W)) = make_float4(t[1][0], t[1][1], t[1][2], t[1][3]);
    *(float4*)(ynew + base + (size_t)2 * (H * W)) =
        make_float4(t[1][0] + t[2][0], t[1][1] + t[2][1], t[1][2] + t[2][2], t[1][3] + t[2][3]);
}

// ---------------------------------------------------------------------------
// Kernel B: P[n][co][t] (padded stride 16), t = r*4+y.
// grid: 64 blocks (8 n x 8 co-blocks of 16); conv_w slice + x column in LDS.
// ---------------------------------------------------------------------------
__global__ __launch_bounds__(256) void kpmat(const float* __restrict__ x,
                                             const float* __restrict__ convw,
                                             float* __restrict__ P) {
    __shared__ float xl[CIN * 4];
    __shared__ float wl[16 * 192];
    const int n = blockIdx.x >> 3;
    const int co0 = (blockIdx.x & 7) * 16;
    const int tid = threadIdx.x;
    {
        int ci = tid >> 2, y = tid & 3;
        xl[tid] = x[(((size_t)n * CIN + ci) * H + y) * W];
    }
    for (int p = tid; p < 16 * 192; p += 256) wl[p] = convw[co0 * 192 + p];
    __syncthreads();
    if (tid < 192) {
        int co = tid / 12, t = tid - co * 12;
        int r = t >> 2, y = t & 3;
        float s = 0.f;
#pragma unroll
        for (int ci = 0; ci < CIN; ++ci) s += wl[co * 192 + ci * 3 + r] * xl[ci * 4 + y];
        P[((size_t)n * COUT + co0 + co) * 16 + t] = s;
    }
}

// ---------------------------------------------------------------------------
// Kernel C: out[n,co,i,j] = sum_t C[t](n,i,j) * P[n,co,t]  (rank-12)
// grid: (i=256, n=8), block 256. Nontemporal float4 stores.
// ---------------------------------------------------------------------------
__global__ __launch_bounds__(256) void kout(const float* __restrict__ ynew,
                                            const float* __restrict__ P,
                                            float* __restrict__ out) {
    __shared__ float Cs[12 * 256];
    __shared__ float Pl[128 * 16];
    const int n = blockIdx.y;
    const int i = blockIdx.x;
    const int tid = threadIdx.x;

    // P slice for this n: already padded [co][16] -> straight vec4 copy
    {
        const f4v* src = (const f4v*)(P + (size_t)n * COUT * 16);
        f4v* dst = (f4v*)Pl;
        dst[tid] = src[tid];
        dst[tid + 256] = src[tid + 256];
    }

    // coefficients for j = tid
    {
        const int j = tid;
        float c[12];
#pragma unroll
        for (int t = 0; t < 12; ++t) c[t] = 0.f;
#pragma unroll
        for (int r = 0; r < 3; ++r) {
            int rowi = 3 * i + r;
            int k = rowi >> 8;
            int i2 = rowi & 255;
            float g = (float)(((k + i2 + j) % 3) - 1) +
                      ynew[((size_t)n * 3 + k) * (H * W) + i2 * W + j];
            float gy = g / 127.5f - 1.0f;
            float iy = ((gy + 1.0f) * 256.0f - 1.0f) * 0.5f;
            float fy = floorf(iy);
            int y0 = (int)fy;
            float w1 = iy - fy;
            if ((unsigned)y0 < 4u) c[r * 4 + y0] += 0.5f * (1.0f - w1);
            int y1 = y0 + 1;
            if ((unsigned)y1 < 4u) c[r * 4 + y1] += 0.5f * w1;
        }
#pragma unroll
        for (int t = 0; t < 12; ++t) Cs[t * 256 + j] = c[t];
    }
    __syncthreads();

    const int jq = (tid & 63) * 4;
    const int cg = tid >> 6;
    float4 cc[12];
#pragma unroll
    for (int t = 0; t < 12; ++t) cc[t] = *(const float4*)&Cs[t * 256 + jq];

    float* op = out + (((size_t)n * COUT) * H + i) * W;
    for (int co = cg * 32; co < cg * 32 + 32; ++co) {
        const float4* pp = (const float4*)&Pl[co * 16];
        float4 P0 = pp[0], P1 = pp[1], P2 = pp[2];
        float pv[12] = {P0.x, P0.y, P0.z, P0.w, P1.x, P1.y, P1.z, P1.w,
                        P2.x, P2.y, P2.z, P2.w};
        f4v a = {0.f, 0.f, 0.f, 0.f};
#pragma unroll
        for (int t = 0; t < 12; ++t) {
            a.x += pv[t] * cc[t].x;
            a.y += pv[t] * cc[t].y;
            a.z += pv[t] * cc[t].z;
            a.w += pv[t] * cc[t].w;
        }
        __builtin_nontemporal_store(a, (f4v*)(op + (size_t)co * (H * W) + jq));
    }
}

// ---------------------------------------------------------------------------
extern "C" void kernel_launch(void* const* d_in, const int* in_sizes, int n_in,
                              void* d_out, int out_size, void* d_ws, size_t ws_size,
                              hipStream_t stream) {
    const float* x = (const float*)d_in[0];      // [8,64,256,256]
    const float* offw = (const float*)d_in[1];   // [6,64,3,3]
    const float* convw = (const float*)d_in[2];  // [128,64,3,1]
    float* out = (float*)d_out;                  // [8,128,256,256]

    const size_t PART_FLOATS = (size_t)G * NB * 3 * H * W;   // 3.15M
    const size_t YNEW_FLOATS = (size_t)NB * 3 * H * W;       // 1.57M
    float* part = (float*)d_ws;
    float* ynew = part + PART_FLOATS;
    float* P = ynew + YNEW_FLOATS;                           // [8][128][16]

    koffset<<<dim3(8, 8, NB * G), 256, 0, stream>>>(x, offw, part);
    kreduce<<<dim3(NB * H * W / 4 / 256), 256, 0, stream>>>(part, ynew);
    kpmat<<<dim3(64), 256, 0, stream>>>(x, convw, P);
    kout<<<dim3(H, NB), 256, 0, stream>>>(ynew, P, out);
}